// Round 1
// baseline (1688.292 us; speedup 1.0000x reference)
//
#include <hip/hip_runtime.h>
#include <math.h>

// Problem constants (fixed by reference: B=2, N=2048, d_model=1024, H=16, D=64)
#define SEQ   2048
#define DM    1024
#define NTOK  4096      // B*SEQ
#define HEADS 16
#define HDIM  64
#define ROPE_SCALE 0.006135923151542565f   // 2*pi/1024

// GEMM tiling
#define TM 64
#define TN 64
#define TK 32

// ---------------------------------------------------------------------------
// Kernel 1: Y = X @ W^T + b for W in {Wq, Wk, Wv} (blockIdx.z selects),
// fused 2D-RoPE for q/k in the epilogue, output layout [B][H][N][D].
// ---------------------------------------------------------------------------
__global__ __launch_bounds__(256) void qkv_rope(
    const float* __restrict__ x,
    const float* __restrict__ Wq, const float* __restrict__ bq,
    const float* __restrict__ Wk, const float* __restrict__ bk,
    const float* __restrict__ Wv, const float* __restrict__ bv,
    const float* __restrict__ qpos, const float* __restrict__ kpos,
    float* __restrict__ qo, float* __restrict__ ko, float* __restrict__ vo)
{
    const int proj = blockIdx.z;                 // 0=q 1=k 2=v
    const float* W   = proj==0 ? Wq : (proj==1 ? Wk : Wv);
    const float* bia = proj==0 ? bq : (proj==1 ? bk : bv);
    float* out       = proj==0 ? qo : (proj==1 ? ko : vo);
    const float* pos = proj==0 ? qpos : kpos;

    __shared__ __align__(16) float As[TK][TM+4]; // [k][m], +4 pad breaks conflicts
    __shared__ __align__(16) float Bs[TK][TN+4]; // [k][n]

    const int tx = threadIdx.x, ty = threadIdx.y;   // 16 x 16
    const int tid = ty*16 + tx;
    const int m0 = blockIdx.y * TM;                 // token tile
    const int n0 = blockIdx.x * TN;                 // out-feature tile

    float acc[4][4] = {};

    for (int k0 = 0; k0 < DM; k0 += TK) {
        // stage 64x32 tiles of X and W (transposed into [k][row]) — 2 float4 each
        for (int f = tid; f < 512; f += 256) {
            const int r = f >> 3, c4 = (f & 7) * 4;
            float4 a = *(const float4*)(x + (size_t)(m0 + r)*DM + k0 + c4);
            As[c4+0][r]=a.x; As[c4+1][r]=a.y; As[c4+2][r]=a.z; As[c4+3][r]=a.w;
            float4 b = *(const float4*)(W + (size_t)(n0 + r)*DM + k0 + c4);
            Bs[c4+0][r]=b.x; Bs[c4+1][r]=b.y; Bs[c4+2][r]=b.z; Bs[c4+3][r]=b.w;
        }
        __syncthreads();
        #pragma unroll
        for (int kk = 0; kk < TK; ++kk) {
            float4 a4 = *(const float4*)&As[kk][ty*4];
            float4 b4 = *(const float4*)&Bs[kk][tx*4];
            const float av[4] = {a4.x,a4.y,a4.z,a4.w};
            const float bv4[4] = {b4.x,b4.y,b4.z,b4.w};
            #pragma unroll
            for (int i=0;i<4;++i)
                #pragma unroll
                for (int j=0;j<4;++j)
                    acc[i][j] += av[i]*bv4[j];
        }
        __syncthreads();
    }

    // epilogue: bias (+RoPE for q/k), store to [B][H][N][D]
    #pragma unroll
    for (int i=0;i<4;++i) {
        const int tok = m0 + ty*4 + i;
        const int b   = tok >> 11;           // /SEQ
        const int n   = tok & (SEQ-1);
        if (proj == 2) {
            #pragma unroll
            for (int j=0;j<4;++j) {
                const int o = n0 + tx*4 + j;
                const int h = o >> 6, dd = o & 63;
                out[(((size_t)(b*HEADS + h))*SEQ + n)*HDIM + dd] = acc[i][j] + bia[o];
            }
        } else {
            // pairs (o, o+1) with o even always land inside one thread's 4 cols
            #pragma unroll
            for (int j=0;j<4;j+=2) {
                const int o = n0 + tx*4 + j;
                const int h = o >> 6, dd = o & 63;       // dd even
                const int plane = (dd < 32) ? 0 : 1;     // x-plane / y-plane
                const float p = pos[((size_t)(b*SEQ + n))*2 + plane];
                // inv_freq[i] = 10000^{-(2i)/32}; 2i == dd&31 (dd even)
                const float e = (float)(dd & 31) * (1.0f/32.0f);
                const float invf = 1.0f / powf(10000.0f, e);
                const float ang = p * ROPE_SCALE * invf;
                float s, c;
                sincosf(ang, &s, &c);
                const float a0 = acc[i][j]   + bia[o];
                const float a1 = acc[i][j+1] + bia[o+1];
                const size_t base = (((size_t)(b*HEADS + h))*SEQ + n)*HDIM + dd;
                out[base]   = a0*c - a1*s;
                out[base+1] = a0*s + a1*c;
            }
        }
    }
}

// ---------------------------------------------------------------------------
// Kernel 2: flash attention fp32, one query per thread.
// grid = (SEQ/256, B*H), block = 256. K/V tiles of 32 keys in LDS,
// uniform-address float4 LDS reads (broadcast, conflict-free).
// Output ao layout [B][N][H][D] (== [token][1024], GEMM-ready).
// ---------------------------------------------------------------------------
#define KB 32

__global__ __launch_bounds__(256) void attn(
    const float* __restrict__ q, const float* __restrict__ k,
    const float* __restrict__ v, float* __restrict__ ao)
{
    const int bh  = blockIdx.y;                       // 0..31
    const int tid = threadIdx.x;
    const int qi  = blockIdx.x*256 + tid;             // query index in [0,SEQ)

    __shared__ __align__(16) float Ks[KB][HDIM+4];
    __shared__ __align__(16) float Vs[KB][HDIM+4];

    const float* qrow = q + ((size_t)bh*SEQ + qi)*HDIM;
    float qr[64];
    #pragma unroll
    for (int d4=0; d4<16; ++d4) {
        float4 t = *(const float4*)(qrow + d4*4);
        qr[d4*4]=t.x; qr[d4*4+1]=t.y; qr[d4*4+2]=t.z; qr[d4*4+3]=t.w;
    }
    float acc[64] = {};
    float mrun = -INFINITY, lrun = 0.f;

    const float* kbase = k + (size_t)bh*SEQ*HDIM;
    const float* vbase = v + (size_t)bh*SEQ*HDIM;

    for (int kt = 0; kt < SEQ; kt += KB) {
        for (int f = tid; f < KB*16; f += 256) {      // 512 float4s: K and V
            const int r = f >> 4, c4 = (f & 15)*4;
            *(float4*)&Ks[r][c4] = *(const float4*)(kbase + (size_t)(kt+r)*HDIM + c4);
            *(float4*)&Vs[r][c4] = *(const float4*)(vbase + (size_t)(kt+r)*HDIM + c4);
        }
        __syncthreads();

        float lg[KB];
        float tmax = -INFINITY;
        #pragma unroll
        for (int j=0;j<KB;++j) {
            float dot = 0.f;
            #pragma unroll
            for (int d4=0; d4<16; ++d4) {
                float4 k4 = *(const float4*)&Ks[j][d4*4];
                dot += qr[d4*4]*k4.x + qr[d4*4+1]*k4.y + qr[d4*4+2]*k4.z + qr[d4*4+3]*k4.w;
            }
            lg[j] = dot * 0.125f;                      // 1/sqrt(64)
            tmax = fmaxf(tmax, lg[j]);
        }
        const float mnew = fmaxf(mrun, tmax);
        const float corr = __expf(mrun - mnew);        // exp(-inf)=0 on first tile
        lrun *= corr;
        #pragma unroll
        for (int d=0; d<64; ++d) acc[d] *= corr;
        #pragma unroll
        for (int j=0;j<KB;++j) {
            const float p = __expf(lg[j] - mnew);
            lrun += p;
            #pragma unroll
            for (int d4=0; d4<16; ++d4) {
                float4 vv = *(const float4*)&Vs[j][d4*4];
                acc[d4*4]   += p*vv.x;
                acc[d4*4+1] += p*vv.y;
                acc[d4*4+2] += p*vv.z;
                acc[d4*4+3] += p*vv.w;
            }
        }
        mrun = mnew;
        __syncthreads();
    }

    const float invl = 1.0f / lrun;
    const int b = bh >> 4, h = bh & 15;
    float* orow = ao + (((size_t)b*SEQ + qi)*HEADS + h)*HDIM;
    #pragma unroll
    for (int d4=0; d4<16; ++d4) {
        float4 t;
        t.x=acc[d4*4]*invl; t.y=acc[d4*4+1]*invl;
        t.z=acc[d4*4+2]*invl; t.w=acc[d4*4+3]*invl;
        *(float4*)(orow + d4*4) = t;
    }
}

// ---------------------------------------------------------------------------
// Kernel 3: out = AO @ Wo^T + bo   (AO is [token][1024] row-major)
// ---------------------------------------------------------------------------
__global__ __launch_bounds__(256) void out_proj(
    const float* __restrict__ ao, const float* __restrict__ Wo,
    const float* __restrict__ bo, float* __restrict__ out)
{
    __shared__ __align__(16) float As[TK][TM+4];
    __shared__ __align__(16) float Bs[TK][TN+4];

    const int tx = threadIdx.x, ty = threadIdx.y;
    const int tid = ty*16 + tx;
    const int m0 = blockIdx.y * TM;
    const int n0 = blockIdx.x * TN;

    float acc[4][4] = {};

    for (int k0 = 0; k0 < DM; k0 += TK) {
        for (int f = tid; f < 512; f += 256) {
            const int r = f >> 3, c4 = (f & 7) * 4;
            float4 a = *(const float4*)(ao + (size_t)(m0 + r)*DM + k0 + c4);
            As[c4+0][r]=a.x; As[c4+1][r]=a.y; As[c4+2][r]=a.z; As[c4+3][r]=a.w;
            float4 b = *(const float4*)(Wo + (size_t)(n0 + r)*DM + k0 + c4);
            Bs[c4+0][r]=b.x; Bs[c4+1][r]=b.y; Bs[c4+2][r]=b.z; Bs[c4+3][r]=b.w;
        }
        __syncthreads();
        #pragma unroll
        for (int kk = 0; kk < TK; ++kk) {
            float4 a4 = *(const float4*)&As[kk][ty*4];
            float4 b4 = *(const float4*)&Bs[kk][tx*4];
            const float av[4] = {a4.x,a4.y,a4.z,a4.w};
            const float bv4[4] = {b4.x,b4.y,b4.z,b4.w};
            #pragma unroll
            for (int i=0;i<4;++i)
                #pragma unroll
                for (int j=0;j<4;++j)
                    acc[i][j] += av[i]*bv4[j];
        }
        __syncthreads();
    }

    #pragma unroll
    for (int i=0;i<4;++i) {
        const int tok = m0 + ty*4 + i;
        #pragma unroll
        for (int j=0;j<4;++j) {
            const int o = n0 + tx*4 + j;
            out[(size_t)tok*DM + o] = acc[i][j] + bo[o];
        }
    }
}

// ---------------------------------------------------------------------------
extern "C" void kernel_launch(void* const* d_in, const int* in_sizes, int n_in,
                              void* d_out, int out_size, void* d_ws, size_t ws_size,
                              hipStream_t stream)
{
    const float* x    = (const float*)d_in[0];
    const float* qpos = (const float*)d_in[1];
    const float* kpos = (const float*)d_in[2];
    const float* Wq   = (const float*)d_in[3];
    const float* bq   = (const float*)d_in[4];
    const float* Wk   = (const float*)d_in[5];
    const float* bk   = (const float*)d_in[6];
    const float* Wv   = (const float*)d_in[7];
    const float* bv   = (const float*)d_in[8];
    const float* Wo   = (const float*)d_in[9];
    const float* bo   = (const float*)d_in[10];
    float* out = (float*)d_out;

    // workspace: q, k, v in [B][H][N][D] + attention-out in [B][N][H*D]
    // 4 * 4,194,304 floats = 64 MiB
    float* qw = (float*)d_ws;
    float* kw = qw + (size_t)NTOK*DM;
    float* vw = kw + (size_t)NTOK*DM;
    float* aw = vw + (size_t)NTOK*DM;

    dim3 blk(16,16);
    qkv_rope<<<dim3(DM/TN, NTOK/TM, 3), blk, 0, stream>>>(
        x, Wq,bq, Wk,bk, Wv,bv, qpos,kpos, qw,kw,vw);
    attn<<<dim3(SEQ/256, 2*HEADS), 256, 0, stream>>>(qw, kw, vw, aw);
    out_proj<<<dim3(DM/TN, NTOK/TM), blk, 0, stream>>>(aw, Wo, bo, out);
}

// Round 2
// 753.224 us; speedup vs baseline: 2.2414x; 2.2414x over previous
//
#include <hip/hip_runtime.h>
#include <math.h>

// Problem constants (fixed by reference: B=2, N=2048, d_model=1024, H=16, D=64)
#define SEQ   2048
#define DM    1024
#define NTOK  4096      // B*SEQ
#define HEADS 16
#define HDIM  64
#define ROPE_SCALE 0.006135923151542565f   // 2*pi/1024

// GEMM tiling
#define TM 64
#define TN 64
#define TK 32

typedef __attribute__((ext_vector_type(8))) short bf16x8;
typedef __attribute__((ext_vector_type(4))) float f32x4;

__device__ __forceinline__ unsigned short f2bf(float f) {
    unsigned int u = __float_as_uint(f);
    return (unsigned short)((u + 0x7FFFu + ((u >> 16) & 1u)) >> 16);
}
__device__ __forceinline__ float bf2f(unsigned short h) {
    return __uint_as_float(((unsigned int)h) << 16);
}

// ---------------------------------------------------------------------------
// Kernel 1: Y = X @ W^T + b for W in {Wq, Wk, Wv} (blockIdx.z selects),
// fused 2D-RoPE for q/k in the epilogue, output layout [B][H][N][D].
// ---------------------------------------------------------------------------
__global__ __launch_bounds__(256) void qkv_rope(
    const float* __restrict__ x,
    const float* __restrict__ Wq, const float* __restrict__ bq,
    const float* __restrict__ Wk, const float* __restrict__ bk,
    const float* __restrict__ Wv, const float* __restrict__ bv,
    const float* __restrict__ qpos, const float* __restrict__ kpos,
    float* __restrict__ qo, float* __restrict__ ko, float* __restrict__ vo)
{
    const int proj = blockIdx.z;                 // 0=q 1=k 2=v
    const float* W   = proj==0 ? Wq : (proj==1 ? Wk : Wv);
    const float* bia = proj==0 ? bq : (proj==1 ? bk : bv);
    float* out       = proj==0 ? qo : (proj==1 ? ko : vo);
    const float* pos = proj==0 ? qpos : kpos;

    __shared__ __align__(16) float As[TK][TM+4];
    __shared__ __align__(16) float Bs[TK][TN+4];

    const int tx = threadIdx.x, ty = threadIdx.y;   // 16 x 16
    const int tid = ty*16 + tx;
    const int m0 = blockIdx.y * TM;
    const int n0 = blockIdx.x * TN;

    float acc[4][4] = {};

    for (int k0 = 0; k0 < DM; k0 += TK) {
        for (int f = tid; f < 512; f += 256) {
            const int r = f >> 3, c4 = (f & 7) * 4;
            float4 a = *(const float4*)(x + (size_t)(m0 + r)*DM + k0 + c4);
            As[c4+0][r]=a.x; As[c4+1][r]=a.y; As[c4+2][r]=a.z; As[c4+3][r]=a.w;
            float4 b = *(const float4*)(W + (size_t)(n0 + r)*DM + k0 + c4);
            Bs[c4+0][r]=b.x; Bs[c4+1][r]=b.y; Bs[c4+2][r]=b.z; Bs[c4+3][r]=b.w;
        }
        __syncthreads();
        #pragma unroll
        for (int kk = 0; kk < TK; ++kk) {
            float4 a4 = *(const float4*)&As[kk][ty*4];
            float4 b4 = *(const float4*)&Bs[kk][tx*4];
            const float av[4] = {a4.x,a4.y,a4.z,a4.w};
            const float bv4[4] = {b4.x,b4.y,b4.z,b4.w};
            #pragma unroll
            for (int i=0;i<4;++i)
                #pragma unroll
                for (int j=0;j<4;++j)
                    acc[i][j] += av[i]*bv4[j];
        }
        __syncthreads();
    }

    #pragma unroll
    for (int i=0;i<4;++i) {
        const int tok = m0 + ty*4 + i;
        const int b   = tok >> 11;
        const int n   = tok & (SEQ-1);
        if (proj == 2) {
            #pragma unroll
            for (int j=0;j<4;++j) {
                const int o = n0 + tx*4 + j;
                const int h = o >> 6, dd = o & 63;
                out[(((size_t)(b*HEADS + h))*SEQ + n)*HDIM + dd] = acc[i][j] + bia[o];
            }
        } else {
            #pragma unroll
            for (int j=0;j<4;j+=2) {
                const int o = n0 + tx*4 + j;
                const int h = o >> 6, dd = o & 63;       // dd even
                const int plane = (dd < 32) ? 0 : 1;
                const float p = pos[((size_t)(b*SEQ + n))*2 + plane];
                const float e = (float)(dd & 31) * (1.0f/32.0f);
                const float invf = 1.0f / powf(10000.0f, e);
                const float ang = p * ROPE_SCALE * invf;
                float s, c;
                sincosf(ang, &s, &c);
                const float a0 = acc[i][j]   + bia[o];
                const float a1 = acc[i][j+1] + bia[o+1];
                const size_t base = (((size_t)(b*HEADS + h))*SEQ + n)*HDIM + dd;
                out[base]   = a0*c - a1*s;
                out[base+1] = a0*s + a1*c;
            }
        }
    }
}

// ---------------------------------------------------------------------------
// Kernel 2: MFMA flash attention.
// Block = 256 threads = 4 waves; wave owns 32 queries (2 M-frags of 16).
// KV tiles of 32 keys staged in LDS as bf16 hi/lo. QK^T via 3-way split
// (hh+hl+lh); softmax on C-layout; P -> bf16 -> LDS transpose -> A-frag;
// PV with V hi/lo (2 MFMAs). Output ao layout [B][N][H][D].
// ---------------------------------------------------------------------------
#define KB 32

__global__ __launch_bounds__(256) void attn_mfma(
    const float* __restrict__ q, const float* __restrict__ k,
    const float* __restrict__ v, float* __restrict__ ao)
{
    const int bh  = blockIdx.y;                 // 0..31
    const int qb0 = blockIdx.x * 128;           // query tile base
    const int tid = threadIdx.x;
    const int lane = tid & 63;
    const int wv   = tid >> 6;                  // wave 0..3
    const int col  = lane & 15;                 // fragment column lane
    const int grp  = lane >> 4;                 // fragment k-group 0..3

    // LDS: K tile [32][72] hi/lo, V^T tile [64][40] hi/lo, P buf per wave [32][40]
    __shared__ __align__(16) unsigned short Khi[KB][72];
    __shared__ __align__(16) unsigned short Klo[KB][72];
    __shared__ __align__(16) unsigned short Vthi[HDIM][40];
    __shared__ __align__(16) unsigned short Vtlo[HDIM][40];
    __shared__ __align__(16) unsigned short Pb[4][32][40];

    const float* kbase = k + (size_t)bh*SEQ*HDIM;
    const float* vbase = v + (size_t)bh*SEQ*HDIM;

    // ---- load Q fragments (hi/lo), A-layout: row = col, k = ks*32+grp*8+j
    bf16x8 qhi[2][2], qlo[2][2];
    #pragma unroll
    for (int mf = 0; mf < 2; ++mf)
        #pragma unroll
        for (int ks = 0; ks < 2; ++ks) {
            const float* p = q + ((size_t)bh*SEQ + qb0 + wv*32 + mf*16 + col)*HDIM
                               + ks*32 + grp*8;
            float4 f0 = ((const float4*)p)[0];
            float4 f1 = ((const float4*)p)[1];
            float fv[8] = {f0.x,f0.y,f0.z,f0.w,f1.x,f1.y,f1.z,f1.w};
            bf16x8 h, l;
            #pragma unroll
            for (int j = 0; j < 8; ++j) {
                unsigned short hb = f2bf(fv[j]);
                h[j] = (short)hb;
                l[j] = (short)f2bf(fv[j] - bf2f(hb));
            }
            qhi[mf][ks] = h; qlo[mf][ks] = l;
        }

    f32x4 o[2][4];
    #pragma unroll
    for (int mf=0; mf<2; ++mf)
        #pragma unroll
        for (int nf=0; nf<4; ++nf)
            o[mf][nf] = (f32x4)0.f;
    float mrun[2][4], lrun[2][4];
    #pragma unroll
    for (int mf=0; mf<2; ++mf)
        #pragma unroll
        for (int r=0; r<4; ++r) { mrun[mf][r] = -INFINITY; lrun[mf][r] = 0.f; }

    for (int kt = 0; kt < SEQ; kt += KB) {
        __syncthreads();   // previous tile fully consumed
        // ---- stage K tile (coalesced): thread -> row tid>>3, cols (tid&7)*8..+7
        {
            const int row = tid >> 3, c0 = (tid & 7) * 8;
            const float* src = kbase + (size_t)(kt + row)*HDIM + c0;
            float4 f0 = ((const float4*)src)[0];
            float4 f1 = ((const float4*)src)[1];
            float fv[8] = {f0.x,f0.y,f0.z,f0.w,f1.x,f1.y,f1.z,f1.w};
            bf16x8 h, l;
            #pragma unroll
            for (int j = 0; j < 8; ++j) {
                unsigned short hb = f2bf(fv[j]);
                h[j] = (short)hb;
                l[j] = (short)f2bf(fv[j] - bf2f(hb));
            }
            *(bf16x8*)&Khi[row][c0] = h;
            *(bf16x8*)&Klo[row][c0] = l;
        }
        // ---- stage V tile transposed: thread -> key tid&31, dims (tid>>5)*8..+7
        {
            const int key = tid & 31, db = tid >> 5;
            const float* src = vbase + (size_t)(kt + key)*HDIM + db*8;
            float4 f0 = ((const float4*)src)[0];
            float4 f1 = ((const float4*)src)[1];
            float fv[8] = {f0.x,f0.y,f0.z,f0.w,f1.x,f1.y,f1.z,f1.w};
            #pragma unroll
            for (int j = 0; j < 8; ++j) {
                unsigned short hb = f2bf(fv[j]);
                Vthi[db*8+j][key] = hb;
                Vtlo[db*8+j][key] = f2bf(fv[j] - bf2f(hb));
            }
        }
        __syncthreads();

        // ---- S = Q @ K^T  (3-way split), S is 32q x 32k per wave
        f32x4 s[2][2];
        #pragma unroll
        for (int mf=0; mf<2; ++mf)
            #pragma unroll
            for (int nf=0; nf<2; ++nf)
                s[mf][nf] = (f32x4)0.f;
        #pragma unroll
        for (int ks = 0; ks < 2; ++ks) {
            bf16x8 kh[2], kl[2];
            #pragma unroll
            for (int nf = 0; nf < 2; ++nf) {
                kh[nf] = *(const bf16x8*)&Khi[nf*16 + col][ks*32 + grp*8];
                kl[nf] = *(const bf16x8*)&Klo[nf*16 + col][ks*32 + grp*8];
            }
            #pragma unroll
            for (int mf = 0; mf < 2; ++mf)
                #pragma unroll
                for (int nf = 0; nf < 2; ++nf) {
                    s[mf][nf] = __builtin_amdgcn_mfma_f32_16x16x32_bf16(qhi[mf][ks], kh[nf], s[mf][nf], 0,0,0);
                    s[mf][nf] = __builtin_amdgcn_mfma_f32_16x16x32_bf16(qlo[mf][ks], kh[nf], s[mf][nf], 0,0,0);
                    s[mf][nf] = __builtin_amdgcn_mfma_f32_16x16x32_bf16(qhi[mf][ks], kl[nf], s[mf][nf], 0,0,0);
                }
        }

        // ---- online softmax on C-layout (row = grp*4+r, col = key)
        #pragma unroll
        for (int mf=0; mf<2; ++mf)
            #pragma unroll
            for (int nf=0; nf<2; ++nf)
                s[mf][nf] *= 0.125f;   // 1/sqrt(64)

        #pragma unroll
        for (int mf = 0; mf < 2; ++mf) {
            #pragma unroll
            for (int r = 0; r < 4; ++r) {
                float m2 = fmaxf(s[mf][0][r], s[mf][1][r]);
                m2 = fmaxf(m2, __shfl_xor(m2, 1, 16));
                m2 = fmaxf(m2, __shfl_xor(m2, 2, 16));
                m2 = fmaxf(m2, __shfl_xor(m2, 4, 16));
                m2 = fmaxf(m2, __shfl_xor(m2, 8, 16));
                const float mnew = fmaxf(mrun[mf][r], m2);
                const float corr = __expf(mrun[mf][r] - mnew);
                mrun[mf][r] = mnew;
                const float p0 = __expf(s[mf][0][r] - mnew);
                const float p1 = __expf(s[mf][1][r] - mnew);
                float ts = p0 + p1;
                ts += __shfl_xor(ts, 1, 16);
                ts += __shfl_xor(ts, 2, 16);
                ts += __shfl_xor(ts, 4, 16);
                ts += __shfl_xor(ts, 8, 16);
                lrun[mf][r] = lrun[mf][r]*corr + ts;
                #pragma unroll
                for (int nf=0; nf<4; ++nf) o[mf][nf][r] *= corr;
                Pb[wv][mf*16 + grp*4 + r][col]      = f2bf(p0);
                Pb[wv][mf*16 + grp*4 + r][16 + col] = f2bf(p1);
            }
        }

        // ---- O += P @ V  (V hi/lo)
        bf16x8 pa[2];
        #pragma unroll
        for (int mf=0; mf<2; ++mf)
            pa[mf] = *(const bf16x8*)&Pb[wv][mf*16 + col][grp*8];
        #pragma unroll
        for (int nf = 0; nf < 4; ++nf) {
            bf16x8 vh = *(const bf16x8*)&Vthi[nf*16 + col][grp*8];
            bf16x8 vl = *(const bf16x8*)&Vtlo[nf*16 + col][grp*8];
            #pragma unroll
            for (int mf = 0; mf < 2; ++mf) {
                o[mf][nf] = __builtin_amdgcn_mfma_f32_16x16x32_bf16(pa[mf], vh, o[mf][nf], 0,0,0);
                o[mf][nf] = __builtin_amdgcn_mfma_f32_16x16x32_bf16(pa[mf], vl, o[mf][nf], 0,0,0);
            }
        }
    }

    // ---- normalize and write out: ao[b][n][h][d]
    const int b = bh >> 4, h = bh & 15;
    #pragma unroll
    for (int mf = 0; mf < 2; ++mf)
        #pragma unroll
        for (int r = 0; r < 4; ++r) {
            const float inv = 1.0f / lrun[mf][r];
            const int n = qb0 + wv*32 + mf*16 + grp*4 + r;
            float* orow = ao + (((size_t)b*SEQ + n)*HEADS + h)*HDIM;
            #pragma unroll
            for (int nf = 0; nf < 4; ++nf)
                orow[nf*16 + col] = o[mf][nf][r] * inv;
        }
}

// ---------------------------------------------------------------------------
// Kernel 3: out = AO @ Wo^T + bo   (AO is [token][1024] row-major)
// ---------------------------------------------------------------------------
__global__ __launch_bounds__(256) void out_proj(
    const float* __restrict__ ao, const float* __restrict__ Wo,
    const float* __restrict__ bo, float* __restrict__ out)
{
    __shared__ __align__(16) float As[TK][TM+4];
    __shared__ __align__(16) float Bs[TK][TN+4];

    const int tx = threadIdx.x, ty = threadIdx.y;
    const int tid = ty*16 + tx;
    const int m0 = blockIdx.y * TM;
    const int n0 = blockIdx.x * TN;

    float acc[4][4] = {};

    for (int k0 = 0; k0 < DM; k0 += TK) {
        for (int f = tid; f < 512; f += 256) {
            const int r = f >> 3, c4 = (f & 7) * 4;
            float4 a = *(const float4*)(ao + (size_t)(m0 + r)*DM + k0 + c4);
            As[c4+0][r]=a.x; As[c4+1][r]=a.y; As[c4+2][r]=a.z; As[c4+3][r]=a.w;
            float4 b = *(const float4*)(Wo + (size_t)(n0 + r)*DM + k0 + c4);
            Bs[c4+0][r]=b.x; Bs[c4+1][r]=b.y; Bs[c4+2][r]=b.z; Bs[c4+3][r]=b.w;
        }
        __syncthreads();
        #pragma unroll
        for (int kk = 0; kk < TK; ++kk) {
            float4 a4 = *(const float4*)&As[kk][ty*4];
            float4 b4 = *(const float4*)&Bs[kk][tx*4];
            const float av[4] = {a4.x,a4.y,a4.z,a4.w};
            const float bv4[4] = {b4.x,b4.y,b4.z,b4.w};
            #pragma unroll
            for (int i=0;i<4;++i)
                #pragma unroll
                for (int j=0;j<4;++j)
                    acc[i][j] += av[i]*bv4[j];
        }
        __syncthreads();
    }

    #pragma unroll
    for (int i=0;i<4;++i) {
        const int tok = m0 + ty*4 + i;
        #pragma unroll
        for (int j=0;j<4;++j) {
            const int o = n0 + tx*4 + j;
            out[(size_t)tok*DM + o] = acc[i][j] + bo[o];
        }
    }
}

// ---------------------------------------------------------------------------
extern "C" void kernel_launch(void* const* d_in, const int* in_sizes, int n_in,
                              void* d_out, int out_size, void* d_ws, size_t ws_size,
                              hipStream_t stream)
{
    const float* x    = (const float*)d_in[0];
    const float* qpos = (const float*)d_in[1];
    const float* kpos = (const float*)d_in[2];
    const float* Wq   = (const float*)d_in[3];
    const float* bq   = (const float*)d_in[4];
    const float* Wk   = (const float*)d_in[5];
    const float* bk   = (const float*)d_in[6];
    const float* Wv   = (const float*)d_in[7];
    const float* bv   = (const float*)d_in[8];
    const float* Wo   = (const float*)d_in[9];
    const float* bo   = (const float*)d_in[10];
    float* out = (float*)d_out;

    float* qw = (float*)d_ws;
    float* kw = qw + (size_t)NTOK*DM;
    float* vw = kw + (size_t)NTOK*DM;
    float* aw = vw + (size_t)NTOK*DM;

    dim3 blk(16,16);
    qkv_rope<<<dim3(DM/TN, NTOK/TM, 3), blk, 0, stream>>>(
        x, Wq,bq, Wk,bk, Wv,bv, qpos,kpos, qw,kw,vw);
    attn_mfma<<<dim3(SEQ/128, 2*HEADS), 256, 0, stream>>>(qw, kw, vw, aw);
    out_proj<<<dim3(DM/TN, NTOK/TM), blk, 0, stream>>>(aw, Wo, bo, out);
}

// Round 3
// 657.453 us; speedup vs baseline: 2.5679x; 1.1457x over previous
//
#include <hip/hip_runtime.h>
#include <math.h>

// Problem constants (fixed by reference: B=2, N=2048, d_model=1024, H=16, D=64)
#define SEQ   2048
#define DM    1024
#define NTOK  4096      // B*SEQ
#define HEADS 16
#define HDIM  64
#define ROPE_SCALE 0.006135923151542565f   // 2*pi/1024
#define L2_10000   13.287712379549449f     // log2(10000)

typedef __attribute__((ext_vector_type(8))) short bf16x8;
typedef __attribute__((ext_vector_type(4))) float f32x4;

__device__ __forceinline__ unsigned short f2bf(float f) {
    unsigned int u = __float_as_uint(f);
    return (unsigned short)((u + 0x7FFFu + ((u >> 16) & 1u)) >> 16);
}
__device__ __forceinline__ float bf2f(unsigned short h) {
    return __uint_as_float(((unsigned int)h) << 16);
}

__device__ __forceinline__ void split8(const float* __restrict__ src, bf16x8& h, bf16x8& l) {
    float4 f0 = ((const float4*)src)[0];
    float4 f1 = ((const float4*)src)[1];
    float fv[8] = {f0.x,f0.y,f0.z,f0.w,f1.x,f1.y,f1.z,f1.w};
    #pragma unroll
    for (int j = 0; j < 8; ++j) {
        unsigned short hb = f2bf(fv[j]);
        h[j] = (short)hb;
        l[j] = (short)f2bf(fv[j] - bf2f(hb));
    }
}

__device__ __forceinline__ void gload16(const void* g, void* l) {
    __builtin_amdgcn_global_load_lds(
        (const __attribute__((address_space(1))) unsigned int*)g,
        (__attribute__((address_space(3))) unsigned int*)l, 16, 0, 0);
}

// ---------------------------------------------------------------------------
// Pack fp32 [R][1024] -> swizzled bf16 hi|lo tiles of 128 rows x 32 k.
// Tile (mt,kt) is 16384 B at (mt*32+kt)*8192 shorts. In-tile byte offset of
// (r,k,part p) = (r*128 + p*64 + k*2) ^ ((r&7)<<4).
// Swizzle spreads the 16 rows of a ds_read_b128 fragment over all 8 16B bank
// slots (2 lanes/slot = conflict-free), while global_load_lds stays linear.
// ---------------------------------------------------------------------------
__global__ __launch_bounds__(256) void pack_swz(
    const float* __restrict__ src, unsigned short* __restrict__ dst)
{
    const int idx = blockIdx.x*256 + threadIdx.x;   // one thread per 8 elements
    const int e = idx * 8;
    const int r = e >> 10, k0 = e & 1023;
    bf16x8 h, l;
    split8(src + (size_t)r*DM + k0, h, l);
    const int mt = r >> 7, rl = r & 127;
    const int kt = k0 >> 5, kl = k0 & 31;
    char* tb = (char*)(dst + ((size_t)(mt*32 + kt))*8192);
    const int sw = (rl & 7) << 4;
    *(bf16x8*)(tb + ((rl*128 + kl*2) ^ sw))      = h;
    *(bf16x8*)(tb + ((rl*128 + 64 + kl*2) ^ sw)) = l;
}

// Fused [Wq;Wk;Wv] variant: rows 0..3071, source row (r&1023) of W[r>>10].
__global__ __launch_bounds__(256) void pack_swz3(
    const float* __restrict__ Wq, const float* __restrict__ Wk,
    const float* __restrict__ Wv, unsigned short* __restrict__ dst)
{
    const int idx = blockIdx.x*256 + threadIdx.x;
    const int e = idx * 8;
    const int r = e >> 10, k0 = e & 1023;
    const int proj = r >> 10;
    const float* W = proj==0 ? Wq : (proj==1 ? Wk : Wv);
    bf16x8 h, l;
    split8(W + (size_t)(r & 1023)*DM + k0, h, l);
    const int mt = r >> 7, rl = r & 127;
    const int kt = k0 >> 5, kl = k0 & 31;
    char* tb = (char*)(dst + ((size_t)(mt*32 + kt))*8192);
    const int sw = (rl & 7) << 4;
    *(bf16x8*)(tb + ((rl*128 + kl*2) ^ sw))      = h;
    *(bf16x8*)(tb + ((rl*128 + 64 + kl*2) ^ sw)) = l;
}

// ---------------------------------------------------------------------------
// Split-bf16 MFMA GEMM: C[M][N] = A[M][1024] @ B[N][1024]^T (+bias/epilogue).
// 128x128 block tile, BK=32, 4 waves (2x2), 4x4 16x16 frags/wave, 3 MFMAs
// per product (hh+hl+lh). Double-buffered LDS, global_load_lds staging.
// mode 0: fused qkv (N=3072): bias + 2D RoPE (q,k), scatter to [B][H][N][D].
// mode 1: out-proj (N=1024): bias, row-major [tok][1024].
// ---------------------------------------------------------------------------
__global__ __launch_bounds__(256) void gemm_mfma(
    const unsigned short* __restrict__ Ap, const unsigned short* __restrict__ Bp,
    const int mode,
    const float* __restrict__ bq, const float* __restrict__ bk,
    const float* __restrict__ bv,
    const float* __restrict__ qpos, const float* __restrict__ kpos,
    float* __restrict__ qo, float* __restrict__ ko, float* __restrict__ vo,
    const float* __restrict__ bo, float* __restrict__ outp)
{
    __shared__ __align__(16) unsigned short Ab[2][8192];
    __shared__ __align__(16) unsigned short Bb[2][8192];

    const int tid = threadIdx.x, lane = tid & 63, wv = tid >> 6;
    const int col = lane & 15, grp = lane >> 4;
    const int wr = wv >> 1, wc = wv & 1;
    const int mt = blockIdx.y, nt = blockIdx.x;

    f32x4 acc[4][4];
    #pragma unroll
    for (int mf=0; mf<4; ++mf)
        #pragma unroll
        for (int nf=0; nf<4; ++nf)
            acc[mf][nf] = (f32x4)0.f;

    auto stage = [&](int buf, int kt) {
        const char* ga = (const char*)(Ap + ((size_t)(mt*32 + kt))*8192);
        const char* gb = (const char*)(Bp + ((size_t)(nt*32 + kt))*8192);
        char* la = (char*)&Ab[buf][0];
        char* lb = (char*)&Bb[buf][0];
        #pragma unroll
        for (int rep = 0; rep < 4; ++rep) {
            const int o = wv*4096 + rep*1024;
            gload16(ga + o + lane*16, la + o);
            gload16(gb + o + lane*16, lb + o);
        }
    };

    stage(0, 0);
    int cur = 0;
    for (int kt = 0; kt < 32; ++kt) {
        __syncthreads();                       // drains vmcnt: buf[cur] ready
        if (kt < 31) stage(cur ^ 1, kt + 1);   // async prefetch next tile
        const char* A = (const char*)&Ab[cur][0];
        const char* B = (const char*)&Bb[cur][0];
        bf16x8 ah[4], al[4], bh[4], bl[4];
        #pragma unroll
        for (int mf = 0; mf < 4; ++mf) {
            const int rl = wr*64 + mf*16 + col;
            const int base = rl*128 + grp*16;
            const int sw = (rl & 7) << 4;
            ah[mf] = *(const bf16x8*)(A + (base ^ sw));
            al[mf] = *(const bf16x8*)(A + ((base + 64) ^ sw));
        }
        #pragma unroll
        for (int nf = 0; nf < 4; ++nf) {
            const int rl = wc*64 + nf*16 + col;
            const int base = rl*128 + grp*16;
            const int sw = (rl & 7) << 4;
            bh[nf] = *(const bf16x8*)(B + (base ^ sw));
            bl[nf] = *(const bf16x8*)(B + ((base + 64) ^ sw));
        }
        #pragma unroll
        for (int mf = 0; mf < 4; ++mf)
            #pragma unroll
            for (int nf = 0; nf < 4; ++nf) {
                acc[mf][nf] = __builtin_amdgcn_mfma_f32_16x16x32_bf16(ah[mf], bh[nf], acc[mf][nf], 0,0,0);
                acc[mf][nf] = __builtin_amdgcn_mfma_f32_16x16x32_bf16(ah[mf], bl[nf], acc[mf][nf], 0,0,0);
                acc[mf][nf] = __builtin_amdgcn_mfma_f32_16x16x32_bf16(al[mf], bh[nf], acc[mf][nf], 0,0,0);
            }
        cur ^= 1;
    }

    // ---- epilogue. C row = m0+wr*64+mf*16+grp*4+i ; C col = n0+wc*64+nf*16+col
    const int m0 = mt*128, n0 = nt*128;
    if (mode == 1) {
        #pragma unroll
        for (int nf = 0; nf < 4; ++nf) {
            const int n = n0 + wc*64 + nf*16 + col;
            const float bn = bo[n];
            #pragma unroll
            for (int mf = 0; mf < 4; ++mf)
                #pragma unroll
                for (int i = 0; i < 4; ++i) {
                    const int tok = m0 + wr*64 + mf*16 + grp*4 + i;
                    outp[(size_t)tok*DM + n] = acc[mf][nf][i] + bn;
                }
        }
    } else {
        const int proj = n0 >> 10;              // whole block is one projection
        const float* bb = proj==0 ? bq : (proj==1 ? bk : bv);
        float* op       = proj==0 ? qo : (proj==1 ? ko : vo);
        const float* pp = proj==0 ? qpos : kpos;
        #pragma unroll
        for (int nf = 0; nf < 4; ++nf) {
            const int n  = n0 + wc*64 + nf*16 + col;
            const int nn = n & 1023;
            const int h  = nn >> 6, dd = nn & 63;
            const float bn = bb[nn];
            if (proj == 2) {
                #pragma unroll
                for (int mf = 0; mf < 4; ++mf)
                    #pragma unroll
                    for (int i = 0; i < 4; ++i) {
                        const int tok = m0 + wr*64 + mf*16 + grp*4 + i;
                        const int b = tok >> 11, sq = tok & 2047;
                        op[(((size_t)(b*HEADS + h))*SEQ + sq)*HDIM + dd] = acc[mf][nf][i] + bn;
                    }
            } else {
                const int plane = dd >> 5;
                const float e = (float)(dd & 30) * (1.0f/32.0f);
                const float invf = exp2f(-L2_10000 * e);
                #pragma unroll
                for (int mf = 0; mf < 4; ++mf)
                    #pragma unroll
                    for (int i = 0; i < 4; ++i) {
                        const int tok = m0 + wr*64 + mf*16 + grp*4 + i;
                        const int b = tok >> 11, sq = tok & 2047;
                        const float pv = pp[((size_t)(b*SEQ + sq))*2 + plane];
                        const float ang = pv * ROPE_SCALE * invf;
                        float s, c;
                        sincosf(ang, &s, &c);
                        const float val = acc[mf][nf][i] + bn;
                        const float prt = __shfl_xor(val, 1);
                        const float res = (dd & 1) ? (prt*s + val*c) : (val*c - prt*s);
                        op[(((size_t)(b*HEADS + h))*SEQ + sq)*HDIM + dd] = res;
                    }
            }
        }
    }
}

// ---------------------------------------------------------------------------
// Kernel: MFMA flash attention (unchanged from round 1).
// ---------------------------------------------------------------------------
#define KB 32

__global__ __launch_bounds__(256) void attn_mfma(
    const float* __restrict__ q, const float* __restrict__ k,
    const float* __restrict__ v, float* __restrict__ ao)
{
    const int bh  = blockIdx.y;
    const int qb0 = blockIdx.x * 128;
    const int tid = threadIdx.x;
    const int lane = tid & 63;
    const int wv   = tid >> 6;
    const int col  = lane & 15;
    const int grp  = lane >> 4;

    __shared__ __align__(16) unsigned short Khi[KB][72];
    __shared__ __align__(16) unsigned short Klo[KB][72];
    __shared__ __align__(16) unsigned short Vthi[HDIM][40];
    __shared__ __align__(16) unsigned short Vtlo[HDIM][40];
    __shared__ __align__(16) unsigned short Pb[4][32][40];

    const float* kbase = k + (size_t)bh*SEQ*HDIM;
    const float* vbase = v + (size_t)bh*SEQ*HDIM;

    bf16x8 qhi[2][2], qlo[2][2];
    #pragma unroll
    for (int mf = 0; mf < 2; ++mf)
        #pragma unroll
        for (int ks = 0; ks < 2; ++ks) {
            const float* p = q + ((size_t)bh*SEQ + qb0 + wv*32 + mf*16 + col)*HDIM
                               + ks*32 + grp*8;
            split8(p, qhi[mf][ks], qlo[mf][ks]);
        }

    f32x4 o[2][4];
    #pragma unroll
    for (int mf=0; mf<2; ++mf)
        #pragma unroll
        for (int nf=0; nf<4; ++nf)
            o[mf][nf] = (f32x4)0.f;
    float mrun[2][4], lrun[2][4];
    #pragma unroll
    for (int mf=0; mf<2; ++mf)
        #pragma unroll
        for (int r=0; r<4; ++r) { mrun[mf][r] = -INFINITY; lrun[mf][r] = 0.f; }

    for (int kt = 0; kt < SEQ; kt += KB) {
        __syncthreads();
        {
            const int row = tid >> 3, c0 = (tid & 7) * 8;
            bf16x8 h, l;
            split8(kbase + (size_t)(kt + row)*HDIM + c0, h, l);
            *(bf16x8*)&Khi[row][c0] = h;
            *(bf16x8*)&Klo[row][c0] = l;
        }
        {
            const int key = tid & 31, db = tid >> 5;
            const float* src = vbase + (size_t)(kt + key)*HDIM + db*8;
            float4 f0 = ((const float4*)src)[0];
            float4 f1 = ((const float4*)src)[1];
            float fv[8] = {f0.x,f0.y,f0.z,f0.w,f1.x,f1.y,f1.z,f1.w};
            #pragma unroll
            for (int j = 0; j < 8; ++j) {
                unsigned short hb = f2bf(fv[j]);
                Vthi[db*8+j][key] = hb;
                Vtlo[db*8+j][key] = f2bf(fv[j] - bf2f(hb));
            }
        }
        __syncthreads();

        f32x4 s[2][2];
        #pragma unroll
        for (int mf=0; mf<2; ++mf)
            #pragma unroll
            for (int nf=0; nf<2; ++nf)
                s[mf][nf] = (f32x4)0.f;
        #pragma unroll
        for (int ks = 0; ks < 2; ++ks) {
            bf16x8 kh[2], kl[2];
            #pragma unroll
            for (int nf = 0; nf < 2; ++nf) {
                kh[nf] = *(const bf16x8*)&Khi[nf*16 + col][ks*32 + grp*8];
                kl[nf] = *(const bf16x8*)&Klo[nf*16 + col][ks*32 + grp*8];
            }
            #pragma unroll
            for (int mf = 0; mf < 2; ++mf)
                #pragma unroll
                for (int nf = 0; nf < 2; ++nf) {
                    s[mf][nf] = __builtin_amdgcn_mfma_f32_16x16x32_bf16(qhi[mf][ks], kh[nf], s[mf][nf], 0,0,0);
                    s[mf][nf] = __builtin_amdgcn_mfma_f32_16x16x32_bf16(qlo[mf][ks], kh[nf], s[mf][nf], 0,0,0);
                    s[mf][nf] = __builtin_amdgcn_mfma_f32_16x16x32_bf16(qhi[mf][ks], kl[nf], s[mf][nf], 0,0,0);
                }
        }

        #pragma unroll
        for (int mf=0; mf<2; ++mf)
            #pragma unroll
            for (int nf=0; nf<2; ++nf)
                s[mf][nf] *= 0.125f;

        #pragma unroll
        for (int mf = 0; mf < 2; ++mf) {
            #pragma unroll
            for (int r = 0; r < 4; ++r) {
                float m2 = fmaxf(s[mf][0][r], s[mf][1][r]);
                m2 = fmaxf(m2, __shfl_xor(m2, 1, 16));
                m2 = fmaxf(m2, __shfl_xor(m2, 2, 16));
                m2 = fmaxf(m2, __shfl_xor(m2, 4, 16));
                m2 = fmaxf(m2, __shfl_xor(m2, 8, 16));
                const float mnew = fmaxf(mrun[mf][r], m2);
                const float corr = __expf(mrun[mf][r] - mnew);
                mrun[mf][r] = mnew;
                const float p0 = __expf(s[mf][0][r] - mnew);
                const float p1 = __expf(s[mf][1][r] - mnew);
                float ts = p0 + p1;
                ts += __shfl_xor(ts, 1, 16);
                ts += __shfl_xor(ts, 2, 16);
                ts += __shfl_xor(ts, 4, 16);
                ts += __shfl_xor(ts, 8, 16);
                lrun[mf][r] = lrun[mf][r]*corr + ts;
                #pragma unroll
                for (int nf=0; nf<4; ++nf) o[mf][nf][r] *= corr;
                Pb[wv][mf*16 + grp*4 + r][col]      = f2bf(p0);
                Pb[wv][mf*16 + grp*4 + r][16 + col] = f2bf(p1);
            }
        }

        bf16x8 pa[2];
        #pragma unroll
        for (int mf=0; mf<2; ++mf)
            pa[mf] = *(const bf16x8*)&Pb[wv][mf*16 + col][grp*8];
        #pragma unroll
        for (int nf = 0; nf < 4; ++nf) {
            bf16x8 vh = *(const bf16x8*)&Vthi[nf*16 + col][grp*8];
            bf16x8 vl = *(const bf16x8*)&Vtlo[nf*16 + col][grp*8];
            #pragma unroll
            for (int mf = 0; mf < 2; ++mf) {
                o[mf][nf] = __builtin_amdgcn_mfma_f32_16x16x32_bf16(pa[mf], vh, o[mf][nf], 0,0,0);
                o[mf][nf] = __builtin_amdgcn_mfma_f32_16x16x32_bf16(pa[mf], vl, o[mf][nf], 0,0,0);
            }
        }
    }

    const int b = bh >> 4, h = bh & 15;
    #pragma unroll
    for (int mf = 0; mf < 2; ++mf)
        #pragma unroll
        for (int r = 0; r < 4; ++r) {
            const float inv = 1.0f / lrun[mf][r];
            const int n = qb0 + wv*32 + mf*16 + grp*4 + r;
            float* orow = ao + (((size_t)b*SEQ + n)*HEADS + h)*HDIM;
            #pragma unroll
            for (int nf = 0; nf < 4; ++nf)
                orow[nf*16 + col] = o[mf][nf][r] * inv;
        }
}

// ---------------------------------------------------------------------------
extern "C" void kernel_launch(void* const* d_in, const int* in_sizes, int n_in,
                              void* d_out, int out_size, void* d_ws, size_t ws_size,
                              hipStream_t stream)
{
    const float* x    = (const float*)d_in[0];
    const float* qpos = (const float*)d_in[1];
    const float* kpos = (const float*)d_in[2];
    const float* Wq   = (const float*)d_in[3];
    const float* bq   = (const float*)d_in[4];
    const float* Wk   = (const float*)d_in[5];
    const float* bk   = (const float*)d_in[6];
    const float* Wv   = (const float*)d_in[7];
    const float* bv   = (const float*)d_in[8];
    const float* Wo   = (const float*)d_in[9];
    const float* bo   = (const float*)d_in[10];
    float* out = (float*)d_out;

    // workspace (80 MB):
    //   qw/kw/vw fp32 [B*H][N][D]                       48 MB
    //   Xp   packed X (also reused for packed attn-out) 16 MB
    //   Wqkvp packed [Wq;Wk;Wv]                         12 MB
    //   Wop  packed Wo                                   4 MB
    // attention output (fp32 [tok][1024]) lives in d_out temporarily.
    float* qw = (float*)d_ws;
    float* kw = qw + (size_t)NTOK*DM;
    float* vw = kw + (size_t)NTOK*DM;
    unsigned short* Xp    = (unsigned short*)(vw + (size_t)NTOK*DM);
    unsigned short* Wqkvp = Xp + (size_t)NTOK*DM*2;      // 8M shorts after Xp
    unsigned short* Wop   = Wqkvp + (size_t)3*DM*DM*2;   // after 6M shorts

    pack_swz <<<2048, 256, 0, stream>>>(x, Xp);          // R=4096
    pack_swz3<<<1536, 256, 0, stream>>>(Wq, Wk, Wv, Wqkvp);
    pack_swz <<< 512, 256, 0, stream>>>(Wo, Wop);        // R=1024

    gemm_mfma<<<dim3(24, 32), 256, 0, stream>>>(
        Xp, Wqkvp, 0, bq, bk, bv, qpos, kpos, qw, kw, vw, nullptr, nullptr);

    attn_mfma<<<dim3(SEQ/128, 2*HEADS), 256, 0, stream>>>(qw, kw, vw, out);

    pack_swz <<<2048, 256, 0, stream>>>(out, Xp);        // pack attn-out (R=4096)

    gemm_mfma<<<dim3(8, 32), 256, 0, stream>>>(
        Xp, Wop, 1, nullptr, nullptr, nullptr, nullptr, nullptr,
        nullptr, nullptr, nullptr, bo, out);
}